// Round 10
// baseline (186.735 us; speedup 1.0000x reference)
//
#include <hip/hip_runtime.h>

// DynamiConv via implicit-im2col f16 MFMA.
// R1: A-pack staged to LDS (-7.5us). R2: dot2 gate, f16 gpart (-3us).
// R3: TH=8 (1.33x halo) 42us. R4/R5: NT pipeline spill/tail, abandoned.
// R6-R9: fence/mega-tile/pins all FLAT at 42.5us across blocks/CU 2-6 and
//   occ 43-59%. Accounting: MFMA 9K + VALU 25K + HBM-share 38K cycles ~= the
//   102K measured ONLY if nothing overlaps: each block is a strict convoy
//   (load burst -> sigma burst -> barrier -> MFMA -> store burst) and
//   nothing anti-aligns resident blocks' phases. fillBuffer hits 6.3 TB/s
//   on this machine; we sit at 2.4.
// R10: producer/consumer wave specialization. 640 thr = 6 P-waves + 4
//   C-waves; block walks NT=4 x-tiles. Each iter: P stages tile t (loads,
//   sigma, dot2 -> lv/gpart buf t&1) WHILE C computes tile t-1 from the
//   other buffer (gate + 2 rows x 18 MFMA + stores). One lgkmcnt+s_barrier
//   per iter; stores drain in background. Memory/VALU/MFMA now overlap by
//   construction, not scheduler luck. LDS 80976 B -> 2 blocks/CU, grid 512
//   (one full-resident round). launch_bounds(640,5): VGPR cap 102, paths
//   ~55-60 -> no spill.
// x[8,32,256,256] f32, W[32,32,3,3], dW[1,32,3,3], bias[32] -> out[8,32,256,256] f32

typedef _Float16 half8 __attribute__((ext_vector_type(8)));
typedef _Float16 half2 __attribute__((ext_vector_type(2)));
typedef float f32x16 __attribute__((ext_vector_type(16)));

#define BATCH 8
#define CIN 32
#define COUT 32
#define TW 32           // spatial tile width (one MFMA n-tile)
#define TH 8            // spatial tile height
#define HTW 34
#define HTH 10
#define CSTR 40         // f16 per position (32 ch + 8 pad) = 80 B stride
#define NCHUNK 18       // K=288 as 18 chunks of 16
#define NLDSA 14        // A chunks staged in LDS; chunks 14..17 in C VGPRs
#define NREGA (NCHUNK - NLDSA)
#define NPOS (HTH*HTW)  // 340 halo positions
#define NT 4            // x-adjacent tiles walked per block
#define NPW 6           // producer waves (384 lanes >= 340 positions)
#define NCW 4           // consumer waves (4 x 2 rows = TH)
#define NTHR ((NPW+NCW)*64)

// Apack = W in per-lane MFMA A order (o=lane&31, c=(q&1)*16+(lane>>5)*8+j, tap=q>>1).
// dwf2[cp][tap] = (dW[2cp][tap], dW[2cp+1][tap]) f16x2, tap-minor.
__global__ __launch_bounds__(256) void prep_pack(const float* __restrict__ w,
                                                 const float* __restrict__ dw,
                                                 _Float16* __restrict__ Apack,
                                                 half2* __restrict__ dwf2) {
  int t = blockIdx.x * 256 + threadIdx.x;
  if (t < 9216) {
    int q = t >> 9, lane = (t >> 3) & 63, j = t & 7;
    int tap = q >> 1, h = q & 1;
    int o = lane & 31, lh = lane >> 5;
    int c = h * 16 + lh * 8 + j;
    Apack[t] = (_Float16)w[o * 288 + c * 9 + tap];
  } else if (t < 9216 + 144) {
    int i = t - 9216;          // i = cp*9 + tap
    int cp = i / 9, tap = i - cp * 9;
    half2 d;
    d.x = (_Float16)dw[(2 * cp) * 9 + tap];
    d.y = (_Float16)dw[(2 * cp + 1) * 9 + tap];
    dwf2[i] = d;
  }
}

__global__ __launch_bounds__(NTHR, 5) void dynconv(
    const float* __restrict__ x, const _Float16* __restrict__ Apack,
    const half2* __restrict__ dwf2, const float* __restrict__ bias,
    float* __restrict__ out) {
  __shared__ __align__(16) _Float16 lvA[NLDSA * 512];    // 14336 B
  __shared__ __align__(16) _Float16 lv[2][NPOS * CSTR];  // 2 x 27200 B
  __shared__ _Float16 gpart[2][9 * NPOS];                // 2 x 6120 B

  // XCD-batch swizzle: XCD k handles batch k; halo re-reads stay in its L2.
  const int bid0 = blockIdx.x;              // grid = 512
  const int bb = bid0 & 7, idx = bid0 >> 3;
  const int xh = idx & 1, yt = idx >> 1;    // yt < 32
  const int x0b = xh * (NT * TW), y0 = yt * TH;
  const int tid = threadIdx.x;
  const int lane = tid & 63;
  const int w8 = tid >> 6;                  // wave id 0..9
  const bool isP = w8 < NPW;

  // ---- A-pack chunks 0..13 -> LDS: 896 half8 units over 640 threads ----
  half8 acopy0 = *(const half8*)(Apack + (tid << 3));   // units 0..639
  half8 acopy1;
  if (tid < NLDSA * 64 - NTHR)
    acopy1 = *(const half8*)(Apack + ((NTHR + tid) << 3));
  *(half8*)(lvA + (tid << 3)) = acopy0;
  if (tid < NLDSA * 64 - NTHR)
    *(half8*)(lvA + ((NTHR + tid) << 3)) = acopy1;

  // ---- consumer-only: A chunks 14..17 in regs (live only on C path) ----
  half8 areg[NREGA];
  if (!isP) {
#pragma unroll
    for (int r = 0; r < NREGA; ++r)
      areg[r] = *(const half8*)(Apack + (((NLDSA + r) * 64 + lane) << 3));
  }

  // ---- producer geometry: one halo position per lane ----
  const bool owner = isP && (tid < NPOS);
  const int yy = tid / HTW, xx = tid - (tid / HTW) * HTW;
  const int gy = y0 + yy - 1;
  const bool rowok = (unsigned)gy < 256u;

  const int ln = lane & 31, lh = lane >> 5;

  for (int t = 0; t <= NT; ++t) {
    // ======== producers: stage tile t into buf t&1 ========
    if (t < NT && owner) {
      const int buf = t & 1;
      const int gx = x0b + t * TW + xx - 1;
      float v[CIN];
      if (rowok && (unsigned)gx < 256u) {
        const int voff = (gy << 8) + gx;    // uniform across c -> saddr loads
#pragma unroll
        for (int c = 0; c < CIN; ++c)
          v[c] = x[(((size_t)(bb * CIN + c)) << 16) + voff];
      } else {
#pragma unroll
        for (int c = 0; c < CIN; ++c) v[c] = 0.f;
      }
      float p[9];
#pragma unroll
      for (int tap = 0; tap < 9; ++tap) p[tap] = 0.f;
      _Float16 hv[CIN];
#pragma unroll
      for (int cp = 0; cp < CIN / 2; ++cp) {
        const float v0 = v[2 * cp], v1 = v[2 * cp + 1];
        const float s0 = __builtin_amdgcn_rcpf(1.f + __expf(-v0));
        const float s1 = __builtin_amdgcn_rcpf(1.f + __expf(-v1));
        half2 s2;
        s2.x = (_Float16)s0;
        s2.y = (_Float16)s1;
        hv[2 * cp] = (_Float16)v0;
        hv[2 * cp + 1] = (_Float16)v1;
#pragma unroll
        for (int tap = 0; tap < 9; ++tap) {
          const half2 d2 = dwf2[cp * 9 + tap];   // uniform -> SGPR operand
#if __has_builtin(__builtin_amdgcn_fdot2)
          p[tap] = __builtin_amdgcn_fdot2(s2, d2, p[tap], false);
#else
          p[tap] += (float)s2.x * (float)d2.x + (float)s2.y * (float)d2.y;
#endif
        }
      }
#pragma unroll
      for (int u = 0; u < 4; ++u)
        *(half8*)(&lv[buf][tid * CSTR + u * 8]) = *(const half8*)(hv + u * 8);
#pragma unroll
      for (int tap = 0; tap < 9; ++tap)
        gpart[buf][tap * NPOS + tid] = (_Float16)p[tap];
    }

    // ======== consumers: compute tile t-1 from buf (t-1)&1 ========
    if (!isP && t > 0) {
      const int tc = t - 1, buf = tc & 1;
      const int x0t = x0b + tc * TW;
#pragma unroll
      for (int rr = 0; rr < 2; ++rr) {
        const int row = ((w8 - NPW) << 1) | rr;

        float gate = 0.f;
#pragma unroll
        for (int ki = 0; ki < 3; ++ki)
#pragma unroll
          for (int kj = 0; kj < 3; ++kj)
            gate += (float)gpart[buf][(ki * 3 + kj) * NPOS + (row + ki) * HTW + ln + kj];

        f32x16 acc;
#pragma unroll
        for (int i = 0; i < 16; ++i) acc[i] = 0.f;

#pragma unroll
        for (int q = 0; q < NCHUNK; ++q) {
          const int tap = q >> 1, h = q & 1;
          const int ki = tap / 3, kj = tap - ki * 3;
          const half8 a = (q < NLDSA)
                              ? *(const half8*)(lvA + ((q * 64 + lane) << 3))
                              : areg[q - NLDSA];
          const int off = ((row + ki) * HTW + ln + kj) * CSTR + h * 16 + lh * 8;
          const half8 bv = *(const half8*)(&lv[buf][off]);   // ds_read_b128
          acc = __builtin_amdgcn_mfma_f32_32x32x16_f16(a, bv, acc, 0, 0, 0);
        }

        // D layout: col=lane&31, row=(reg&3)+8*(reg>>2)+4*(lane>>5)
        const int voff_out = ((y0 + row) << 8) + x0t + ln;
#pragma unroll
        for (int reg = 0; reg < 16; ++reg) {
          const int o = (reg & 3) + 8 * (reg >> 2) + 4 * lh;
          out[(((size_t)(bb * COUT + o)) << 16) + voff_out] = acc[reg] * gate + bias[o];
        }
      }
    }

    // RAW barrier: drain LDS ops only; C's global stores drain in background.
    asm volatile("s_waitcnt lgkmcnt(0)" ::: "memory");
    __builtin_amdgcn_s_barrier();
    asm volatile("" ::: "memory");
  }
}

extern "C" void kernel_launch(void* const* d_in, const int* in_sizes, int n_in,
                              void* d_out, int out_size, void* d_ws, size_t ws_size,
                              hipStream_t stream) {
  const float* x    = (const float*)d_in[0];
  const float* wgt  = (const float*)d_in[1];
  const float* dw   = (const float*)d_in[2];
  const float* bias = (const float*)d_in[3];
  float* out = (float*)d_out;

  _Float16* Apack = (_Float16*)d_ws;                  // 9216 f16 = 18432 B
  half2* dwf2     = (half2*)((char*)d_ws + 18432);    // 144 half2 = 576 B

  prep_pack<<<(9216 + 144 + 255) / 256, 256, 0, stream>>>(wgt, dw, Apack, dwf2);
  dynconv<<<BATCH * 32 * (256 / (NT * TW)), NTHR, 0, stream>>>(x, Apack, dwf2, bias, out);
}

// Round 11
// 142.436 us; speedup vs baseline: 1.3110x; 1.3110x over previous
//
#include <hip/hip_runtime.h>

// DynamiConv via implicit-im2col f16 MFMA.
// R1: A-pack staged to LDS (-7.5us). R2: dot2 gate, f16 gpart (-3us).
// R3: TH=8 (1.33x halo) 42us. R4/R5: NT pipeline spill, abandoned.
// R6-R9: fence/mega-tile/pins flat; R10 P/C waves spilled (WRITE +42MB).
//   R9/R10 also showed VGPR_Count excludes accum bank -> R6-R9 "engagement"
//   reads were invalid; serialized-staging-loads never actually refuted.
//   Accounting: ~25-30K cy/block observed vs ~7K counted work; 32 staging
//   loads x ~900cy serialized matches the gap. All prior fixes tried to fix
//   it THROUGH the register allocator.
// R11: take registers out of staging: global_load_lds width=16 DMA.
//   Per channel, 2 insts load the 10x40-dword aligned halo window (1KB per
//   inst, 64 DMA insts/block replace 320 scalar loads; fire-and-forget,
//   zero VGPR liveness). Owners then ds_read 32 ch from xstage, sigma/dot2
//   in regs, and lv/gpart OVERLAY the xstage arena (extra barrier phase):
//   LDS = 51200 arena + 14336 lvA = 65536 -> 2 blocks/CU, grid 2048.
// x[8,32,256,256] f32, W[32,32,3,3], dW[1,32,3,3], bias[32] -> out[8,32,256,256] f32

typedef _Float16 half8 __attribute__((ext_vector_type(8)));
typedef _Float16 half2 __attribute__((ext_vector_type(2)));
typedef float f32x16 __attribute__((ext_vector_type(16)));

#define BATCH 8
#define CIN 32
#define COUT 32
#define TW 32           // spatial tile width (one MFMA n-tile)
#define TH 8            // spatial tile height: 8 rows, 1 per wave, 512 thr
#define HTW 34
#define HTH 10
#define XW 40           // aligned halo window width in dwords (x0-4 .. x0+36)
#define CSTR 40         // f16 per position (32 ch + 8 pad) = 80 B stride
#define NCHUNK 18       // K=288 as 18 chunks of 16
#define NLDSA 14        // A chunks staged in LDS; chunks 14..17 live in VGPRs
#define NREGA (NCHUNK - NLDSA)
#define NPOS (HTH*HTW)  // 340 halo positions (one owner thread each)

// Apack = W in per-lane MFMA A order (o=lane&31, c=(q&1)*16+(lane>>5)*8+j, tap=q>>1).
// dwf2[cp][tap] = (dW[2cp][tap], dW[2cp+1][tap]) f16x2, tap-minor.
__global__ __launch_bounds__(256) void prep_pack(const float* __restrict__ w,
                                                 const float* __restrict__ dw,
                                                 _Float16* __restrict__ Apack,
                                                 half2* __restrict__ dwf2) {
  int t = blockIdx.x * 256 + threadIdx.x;
  if (t < 9216) {
    int q = t >> 9, lane = (t >> 3) & 63, j = t & 7;
    int tap = q >> 1, h = q & 1;
    int o = lane & 31, lh = lane >> 5;
    int c = h * 16 + lh * 8 + j;
    Apack[t] = (_Float16)w[o * 288 + c * 9 + tap];
  } else if (t < 9216 + 144) {
    int i = t - 9216;          // i = cp*9 + tap
    int cp = i / 9, tap = i - cp * 9;
    half2 d;
    d.x = (_Float16)dw[(2 * cp) * 9 + tap];
    d.y = (_Float16)dw[(2 * cp + 1) * 9 + tap];
    dwf2[i] = d;
  }
}

__global__ __launch_bounds__(512, 4) void dynconv(
    const float* __restrict__ x, const _Float16* __restrict__ Apack,
    const half2* __restrict__ dwf2, const float* __restrict__ bias,
    float* __restrict__ out) {
  // Arena phase 1-2: xstage f32 [32 ch][10 rows][40 cols] = 51200 B.
  // Arena phase 3-4: lv f16 [340][CSTR] = 27200 B at +0; gpart [9][340] f16
  //   = 6120 B at +27200. Overlay is safe: barrier separates last xstage
  //   read from first lv/gpart write.
  __shared__ __align__(16) unsigned char arena[32 * HTH * XW * 4];
  __shared__ __align__(16) _Float16 lvA[NLDSA * 512];  // 14336 B: A chunks 0..13

  float* xstage = (float*)arena;
  _Float16* lv = (_Float16*)arena;
  _Float16* gpart = (_Float16*)(arena + NPOS * CSTR * 2);

  // XCD-batch swizzle: XCD k handles batch k; halo re-reads stay in its L2.
  const int bid0 = blockIdx.x;              // grid = 2048
  const int bb = bid0 & 7, idx = bid0 >> 3;
  const int xt = idx & 7, yt = idx >> 3;    // yt < 32
  const int x0 = xt * TW, y0 = yt * TH;
  const int tid = threadIdx.x;
  const int lane = tid & 63;
  const int w8 = tid >> 6;                  // wave id 0..7

  // ---- A-pack chunks 0..13 -> LDS: 896 half8 units over 512 threads ----
  half8 acopy0 = *(const half8*)(Apack + (tid << 3));
  half8 acopy1;
  if (tid < NLDSA * 64 - 512)
    acopy1 = *(const half8*)(Apack + ((512 + tid) << 3));
  *(half8*)(lvA + (tid << 3)) = acopy0;
  if (tid < NLDSA * 64 - 512)
    *(half8*)(lvA + ((512 + tid) << 3)) = acopy1;

  // ---- staging phase 1: DMA x halo window into xstage (no VGPR transit).
  // Wave w8 handles channels c = w8, w8+8, w8+16, w8+24; per channel the
  // 10x40-dword window = 100 lane-units of 16 B -> 2 insts (u = j*64+lane,
  // exec-masked to u<100). Global addr 16B-aligned; OOB rows/cols clamped
  // (garbage loaded there is never read: owners zero OOB positions).
#pragma unroll
  for (int k = 0; k < 4; ++k) {
    const int c = (k << 3) | w8;
#pragma unroll
    for (int j = 0; j < 2; ++j) {
      const int u = (j << 6) | lane;
      if (u < HTH * (XW / 4)) {             // 100 units
        const int r = u / (XW / 4);         // row 0..9
        const int g = u - r * (XW / 4);     // 4-dword group 0..9
        int gy = y0 + r - 1;
        gy = gy < 0 ? 0 : (gy > 255 ? 255 : gy);
        int gc = x0 - 4 + (g << 2);
        gc = gc < 0 ? 0 : (gc > 252 ? 252 : gc);
        const float* src = x + (((size_t)(bb * CIN + c)) << 16) + (gy << 8) + gc;
        __builtin_amdgcn_global_load_lds(
            (const __attribute__((address_space(1))) void*)src,
            (__attribute__((address_space(3))) void*)(xstage + c * (HTH * XW) + (j << 8)),
            16, 0, 0);
      }
    }
  }

  __syncthreads();  // barrier 1: DMA + lvA writes complete

  // ---- staging phase 2: owners read 32 ch from xstage, sigma + gate ----
  const bool owner = tid < NPOS;
  float p[9];
  _Float16 hv[CIN];
  if (owner) {
    const int yy = tid / HTW, xx = tid - (tid / HTW) * HTW;
    const int gy = y0 + yy - 1, gx = x0 + xx - 1;
    float v[CIN];
    if ((unsigned)gy < 256u && (unsigned)gx < 256u) {
      const int base = yy * XW + xx + 3;    // window col = gx-(x0-4) = xx+3
#pragma unroll
      for (int c = 0; c < CIN; ++c)
        v[c] = xstage[c * (HTH * XW) + base];   // ds_read_b32, conflict-free
    } else {
#pragma unroll
      for (int c = 0; c < CIN; ++c) v[c] = 0.f;
    }
#pragma unroll
    for (int tap = 0; tap < 9; ++tap) p[tap] = 0.f;
#pragma unroll
    for (int cp = 0; cp < CIN / 2; ++cp) {
      const float v0 = v[2 * cp], v1 = v[2 * cp + 1];
      const float s0 = __builtin_amdgcn_rcpf(1.f + __expf(-v0));
      const float s1 = __builtin_amdgcn_rcpf(1.f + __expf(-v1));
      half2 s2;
      s2.x = (_Float16)s0;
      s2.y = (_Float16)s1;
      hv[2 * cp] = (_Float16)v0;
      hv[2 * cp + 1] = (_Float16)v1;
#pragma unroll
      for (int tap = 0; tap < 9; ++tap) {
        const half2 d2 = dwf2[cp * 9 + tap];   // uniform -> SGPR operand
#if __has_builtin(__builtin_amdgcn_fdot2)
        p[tap] = __builtin_amdgcn_fdot2(s2, d2, p[tap], false);
#else
        p[tap] += (float)s2.x * (float)d2.x + (float)s2.y * (float)d2.y;
#endif
      }
    }
  }

  __syncthreads();  // barrier 2: all xstage reads done before overlay write

  // ---- staging phase 3: write f16 values + gate partials (overlay) ----
  if (owner) {
#pragma unroll
    for (int u = 0; u < 4; ++u)
      *(half8*)(lv + tid * CSTR + u * 8) = *(const half8*)(hv + u * 8);
#pragma unroll
    for (int tap = 0; tap < 9; ++tap)
      gpart[tap * NPOS + tid] = (_Float16)p[tap];
  }

  // A-pack register chunks 14..17: issued here so their regs aren't live
  // earlier; latency hides under the barrier + gate compute.
  half8 areg[NREGA];
#pragma unroll
  for (int r = 0; r < NREGA; ++r)
    areg[r] = *(const half8*)(Apack + (((NLDSA + r) * 64 + lane) << 3));

  __syncthreads();  // barrier 3

  // ---- compute: wave w8 owns tile row y0+w8; 18 chunks, 1 MFMA each ----
  const int ln = lane & 31, lh = lane >> 5;

  float gate = 0.f;
#pragma unroll
  for (int ki = 0; ki < 3; ++ki)
#pragma unroll
    for (int kj = 0; kj < 3; ++kj)
      gate += (float)gpart[(ki * 3 + kj) * NPOS + (w8 + ki) * HTW + ln + kj];

  f32x16 acc;
#pragma unroll
  for (int i = 0; i < 16; ++i) acc[i] = 0.f;

#pragma unroll
  for (int q = 0; q < NCHUNK; ++q) {
    const int tap = q >> 1, h = q & 1;
    const int ki = tap / 3, kj = tap - ki * 3;
    const half8 a = (q < NLDSA)
                        ? *(const half8*)(lvA + ((q * 64 + lane) << 3))  // LDS, lane-linear
                        : areg[q - NLDSA];                               // VGPR-resident
    const int off = ((w8 + ki) * HTW + ln + kj) * CSTR + h * 16 + lh * 8;
    const half8 bv = *(const half8*)(lv + off);   // ds_read_b128
    acc = __builtin_amdgcn_mfma_f32_32x32x16_f16(a, bv, acc, 0, 0, 0);
  }

  // ---- epilogue: D layout col=lane&31, row=(reg&3)+8*(reg>>2)+4*(lane>>5) ----
  const int voff_out = ((y0 + w8) << 8) + x0 + ln;
#pragma unroll
  for (int reg = 0; reg < 16; ++reg) {
    const int o = (reg & 3) + 8 * (reg >> 2) + 4 * lh;
    out[(((size_t)(bb * COUT + o)) << 16) + voff_out] = acc[reg] * gate + bias[o];
  }
}

extern "C" void kernel_launch(void* const* d_in, const int* in_sizes, int n_in,
                              void* d_out, int out_size, void* d_ws, size_t ws_size,
                              hipStream_t stream) {
  const float* x    = (const float*)d_in[0];
  const float* wgt  = (const float*)d_in[1];
  const float* dw   = (const float*)d_in[2];
  const float* bias = (const float*)d_in[3];
  float* out = (float*)d_out;

  _Float16* Apack = (_Float16*)d_ws;                  // 9216 f16 = 18432 B
  half2* dwf2     = (half2*)((char*)d_ws + 18432);    // 144 half2 = 576 B

  prep_pack<<<(9216 + 144 + 255) / 256, 256, 0, stream>>>(wgt, dw, Apack, dwf2);
  dynconv<<<BATCH * 32 * 8, 512, 0, stream>>>(x, Apack, dwf2, bias, out);
}